// Round 15
// baseline (199.254 us; speedup 1.0000x reference)
//
#include <hip/hip_runtime.h>
#include <hip/hip_bf16.h>
#include <cstdint>
#include <cstddef>

typedef __bf16 bf16_t;
typedef bf16_t bf16x8 __attribute__((ext_vector_type(8)));
typedef bf16_t bf16x4 __attribute__((ext_vector_type(4)));
typedef float  f32x4  __attribute__((ext_vector_type(4)));
typedef unsigned int u32;

#define BROWS 4096
#define NV    8192
#define KD    1024
#define NT    32    // GEMM K-tiles (1024 / 32)
#define ST    48    // marginal buckets (6 concepts x 8)
#define LOG2E 1.44269504088896340736f

// async global->LDS, 16B per lane; LDS dst is wave-uniform base + lane*16
#define GLL(gsrc, ldst) \
  __builtin_amdgcn_global_load_lds((const __attribute__((address_space(1))) u32*)(gsrc), \
                                   (__attribute__((address_space(3))) u32*)(ldst), 16, 0, 0)
#define FENCE asm volatile("" ::: "memory")

// ---------------- prep: E/W f32->bf16 + swizzle-baked S2^T, one launch ----
// s2t[b][ig] = indicator(digit_c(vs[ig ^ ((b&7)<<3)]) == d), b = c*8+d
// (the XOR bakes the epilogue's 16B-chunk LDS swizzle; rule #21 both-sides).
__global__ void prep_kernel(const float* __restrict__ E, const float* __restrict__ W,
                            const int* __restrict__ vs,
                            bf16_t* __restrict__ Eb, bf16_t* __restrict__ Wb,
                            bf16_t* __restrict__ s2t) {
  const int nE = BROWS * KD / 4;       // float4 units
  const int nW = NV * KD / 4;
  const int nS = ST * NV / 8;          // bf16x8 units
  const int nT = nE + nW + nS;
  int idx = blockIdx.x * blockDim.x + threadIdx.x;
  int stride = gridDim.x * blockDim.x;
  for (int i = idx; i < nT; i += stride) {
    if (i < nE + nW) {
      const float4* s; bf16x4* d; int j;
      if (i < nE) { s = (const float4*)E; d = (bf16x4*)Eb; j = i; }
      else        { s = (const float4*)W; d = (bf16x4*)Wb; j = i - nE; }
      float4 v = s[j];
      bf16x4 o;
      o[0] = (bf16_t)v.x; o[1] = (bf16_t)v.y; o[2] = (bf16_t)v.z; o[3] = (bf16_t)v.w;
      d[j] = o;
    } else {
      int u  = i - nE - nW;            // bf16x8 unit of s2t
      int b  = u >> 10;                // bucket row (NV/8 = 1024 units/row)
      int i0 = (u & 1023) * 8;
      int base = i0 ^ ((b & 7) << 3);  // swizzle-baked source index
      int c = b >> 3, d = b & 7, sh = 15 - 3 * c;
      bf16x8 o;
#pragma unroll
      for (int e = 0; e < 8; ++e)
        o[e] = (bf16_t)((((vs[base + e] >> sh) & 7) == d) ? 1.0f : 0.0f);
      *(bf16x8*)(s2t + (size_t)b * NV + i0) = o;
    }
  }
}

// ---------------- fused GEMM + exp + marginal ----------------
// D[i=state][j=batch] = sum_k W[i][k]*E[j][k]; 256x256 tile, BK=32, 8 waves
// (wm: 2 state-halves x wn: 4 batch-quarters).
// THIS ROUND: A (W) fragments read DIRECT from global (L2-resident: 2MB W
// working set per XCD; each frag-load = 16 full 64B lines, 4 lanes/line).
// Only B (E) staged in LDS (16KB/tile double-buffered) -> LDS-port demand
// drops 320KB -> 48KB per window (was the binding resource at ~3760 cyc vs
// MFMA 2483). Per K-tile: {8 A global b128 loads, 2 GLL B-stage(kt+1),
// 4 B ds_reads, 32 MFMA, vmcnt(0)+sched_barrier+s_barrier}.
// B swizzle (T2, 64B rows) unchanged/proven: phys = logical ^ ((row&6)<<3);
// staging source pre-permuted kslot = (l&3)^((l>>3)&3) (rule #21 involution).
// Epilogue: R10-verbatim (exp-tile swizzled LDS + GLL-staged swizzle-baked s2t).
__global__ __launch_bounds__(512, 2)
void gemm_fused_kernel(const bf16_t* __restrict__ W, const bf16_t* __restrict__ E,
                       const float* __restrict__ bias, const bf16_t* __restrict__ s2t,
                       float* __restrict__ part) {
  __shared__ __align__(16) char lds[90112];  // main: B dbuf [0,32K); epi: exp [0,64K)+s2t [64K,88K)

  const int t    = threadIdx.x;
  const int lane = t & 63;
  const int wv   = t >> 6;      // 0..7
  const int wm   = wv >> 2;     // 0..1  (state half)
  const int wn   = wv & 3;      // 0..3  (batch quarter)
  const int fr   = lane & 15;
  const int fq   = lane >> 4;

  // XCD swizzle: 512 blocks % 8 == 0 -> simple form bijective
  int bid = blockIdx.x;
  int wg  = (bid & 7) * 64 + (bid >> 3);
  const int stile = wg >> 4;    // 0..31 (state tile)
  const int btile = wg & 15;    // 0..15 (batch tile)
  const int st0 = stile * 256;
  const int bt0 = btile * 256;

  // ---- B staging geometry: tile = 256 rows x 32 k = 16KB = 16 chunks ----
  const int srow = lane >> 2;
  const int skel = ((lane & 3) ^ ((lane >> 3) & 3)) * 8;
  const bf16_t* bptr = E + (size_t)(bt0 + wv * 32 + srow) * KD + skel;
  const int dchunk = wv * 2048;            // wave's 2-chunk base in B region

  // ---- B ds_read geometry: row stride 64B; phys = logical ^ ((row&6)<<3) ----
  const int xsw    = (fr & 6) << 3;
  const int b_base = wn * 4096 + ((fr * 64 + fq * 16) ^ xsw);

  // ---- A direct-load geometry: row = st0 + wm*128 + m*16 + fr, k = kt*32 + fq*8
  const bf16_t* aBase = W + (size_t)(st0 + wm * 128 + fr) * KD + fq * 8;

  f32x4 acc[8][4] = {};

  // ---- prologue: stage B kt0, drain, barrier ----
  GLL(bptr,           &lds[dchunk]);
  GLL(bptr + 16 * KD, &lds[dchunk + 1024]);
  asm volatile("s_waitcnt vmcnt(0)" ::: "memory");
  __builtin_amdgcn_s_barrier();
  FENCE;

  int cur = 0;
  for (int kt = 0; kt < NT; ++kt) {
    const char* bufp = &lds[cur * 16384];
    char* nbuf = &lds[(cur ^ 1) * 16384];
    const bool pf = (kt + 1 < NT);

    bf16x8 a[8], b[4];

    // A fragments direct from global (L2); 16 full lines per load
#pragma unroll
    for (int m = 0; m < 8; ++m)
      a[m] = *(const bf16x8*)(aBase + (size_t)m * 16 * KD + kt * 32);

    // stage next B tile (2 x global_load_lds)
    if (pf) {
      GLL(bptr + (kt + 1) * 32,           &nbuf[dchunk]);
      GLL(bptr + (kt + 1) * 32 + 16 * KD, &nbuf[dchunk + 1024]);
    }

    // B fragments from LDS (4 x ds_read_b128, conflict-free swizzle)
#pragma unroll
    for (int n = 0; n < 4; ++n)
      b[n] = *(const bf16x8*)(bufp + b_base + n * 1024);

    __builtin_amdgcn_s_setprio(1);
#pragma unroll
    for (int m = 0; m < 8; ++m)
#pragma unroll
      for (int n = 0; n < 4; ++n)
        acc[m][n] = __builtin_amdgcn_mfma_f32_16x16x32_bf16(a[m], b[n], acc[m][n], 0, 0, 0);
    __builtin_amdgcn_s_setprio(0);

    asm volatile("s_waitcnt vmcnt(0)" ::: "memory");
    __builtin_amdgcn_sched_barrier(0);
    __builtin_amdgcn_s_barrier();
    FENCE;
    cur ^= 1;
  }

  // ================= fused epilogue (R10-verbatim) =================
  // exp-tile [128 rows][512B] at 0, XOR-swizzled; s2t tile [48][512B] at 65536
  // (swizzle baked into s2t by prep_kernel).
  char* const ldsf = &lds[0];
  {
#pragma unroll
    for (int q = 0; q < 3; ++q) {
      const bf16_t* src = s2t + (size_t)(wv * 6 + q * 2 + (lane >> 5)) * NV
                          + st0 + (lane & 31) * 8;
      GLL(src, ldsf + 65536 + wv * 3072 + q * 1024);
    }
  }

  // part layout: [batch][stile][ST]  (contiguous 1536 floats per batch row)
  float* const ppart = part + (size_t)bt0 * (32 * ST) + (size_t)stile * ST;

#pragma unroll
  for (int pass = 0; pass < 2; ++pass) {
    if ((wn >> 1) == pass) {
#pragma unroll
      for (int m = 0; m < 8; ++m) {
        const float4 bb = *(const float4*)&bias[st0 + wm * 128 + m * 16 + fq * 4];
#pragma unroll
        for (int n = 0; n < 4; ++n) {
          bf16x4 ev;
          ev[0] = (bf16_t)exp2f((acc[m][n][0] + bb.x) * LOG2E);
          ev[1] = (bf16_t)exp2f((acc[m][n][1] + bb.y) * LOG2E);
          ev[2] = (bf16_t)exp2f((acc[m][n][2] + bb.z) * LOG2E);
          ev[3] = (bf16_t)exp2f((acc[m][n][3] + bb.w) * LOG2E);
          const int jh = (wn & 1) * 64 + n * 16 + fr;          // half-local batch row
          const int ib = (wm * 128 + m * 16 + fq * 4) * 2;     // state byte offset
          *(bf16x4*)(ldsf + jh * 512 + (ib ^ ((fr & 7) << 4))) = ev;
        }
      }
    }
    if (pass == 0) asm volatile("s_waitcnt vmcnt(0)" ::: "memory");  // S2T resident
    __syncthreads();

    // marginal MFMA (16x16x32): D[j_local][bucket] = exp-tile . S
    f32x4 acc2[3] = {{0.f,0.f,0.f,0.f},{0.f,0.f,0.f,0.f},{0.f,0.f,0.f,0.f}};
#pragma unroll
    for (int k2 = 0; k2 < 8; ++k2) {
      const int ko2 = (k2 * 64 + fq * 16) ^ ((fr & 7) << 4);
      const bf16x8 ea = *(const bf16x8*)(ldsf + (wv * 16 + fr) * 512 + ko2);
#pragma unroll
      for (int n2 = 0; n2 < 3; ++n2) {
        const bf16x8 sb = *(const bf16x8*)(ldsf + 65536 + (n2 * 16 + fr) * 512 + ko2);
        acc2[n2] = __builtin_amdgcn_mfma_f32_16x16x32_bf16(ea, sb, acc2[n2], 0, 0, 0);
      }
    }
    const int jg = pass * 128 + wv * 16 + fq * 4;
#pragma unroll
    for (int n2 = 0; n2 < 3; ++n2)
#pragma unroll
      for (int r = 0; r < 4; ++r)
        ppart[(size_t)(jg + r) * (32 * ST) + n2 * 16 + fr] = acc2[n2][r];
    __syncthreads();
  }
}

// ---------------- reduce partials over 32 state-tiles + normalize ----------------
// part[batch][stile][ST] contiguous 6 KB per batch row; wave w -> batch b0+w.
__global__ __launch_bounds__(256)
void reduce_kernel(const float* __restrict__ part, float* __restrict__ out) {
  const int w    = threadIdx.x >> 6;
  const int lane = threadIdx.x & 63;
  const int b    = blockIdx.x * 4 + w;

  const float* p = part + (size_t)b * (32 * ST);
  __shared__ float red[4][ST];
  if (lane < ST) {
    float acc = 0.f;
#pragma unroll
    for (int mt = 0; mt < 32; ++mt)
      acc += p[mt * ST + lane];
    red[w][lane] = acc;
  }
  __syncthreads();
  if (lane < ST) {
    const float* fin = red[w];
    float total = fin[0] + fin[1] + fin[2] + fin[3] + fin[4] + fin[5] + fin[6] + fin[7];
    out[(size_t)(lane >> 3) * BROWS * 8 + (size_t)b * 8 + (lane & 7)] = red[w][lane] / total;
  }
}

// ---------------- launch ----------------
extern "C" void kernel_launch(void* const* d_in, const int* in_sizes, int n_in,
                              void* d_out, int out_size, void* d_ws, size_t ws_size,
                              hipStream_t stream) {
  const float* E    = (const float*)d_in[0];
  const float* W    = (const float*)d_in[1];
  const float* bias = (const float*)d_in[2];
  const int*   vs   = (const int*)d_in[3];
  float* out = (float*)d_out;

  char* ws = (char*)d_ws;
  size_t off = 0;
  bf16_t* Eb   = (bf16_t*)(ws + off); off += (size_t)BROWS * KD * 2;           // 8 MB
  bf16_t* Wb   = (bf16_t*)(ws + off); off += (size_t)NV * KD * 2;              // 16 MB
  bf16_t* s2t  = (bf16_t*)(ws + off); off += (size_t)ST * NV * 2;              // 786 KB
  float*  part = (float*)(ws + off);  off += (size_t)BROWS * 32 * ST * 4;      // 25 MB

  prep_kernel<<<3072, 256, 0, stream>>>(E, W, vs, Eb, Wb, s2t);
  gemm_fused_kernel<<<512, 512, 0, stream>>>(Wb, Eb, bias, s2t, part);
  reduce_kernel<<<BROWS / 4, 256, 0, stream>>>(part, out);
}

// Round 16
// 98.973 us; speedup vs baseline: 2.0132x; 2.0132x over previous
//
#include <hip/hip_runtime.h>
#include <hip/hip_bf16.h>
#include <cstdint>
#include <cstddef>

typedef __bf16 bf16_t;
typedef bf16_t bf16x8 __attribute__((ext_vector_type(8)));
typedef bf16_t bf16x4 __attribute__((ext_vector_type(4)));
typedef float  f32x4  __attribute__((ext_vector_type(4)));
typedef unsigned int u32;

#define BROWS 4096
#define NV    8192
#define KD    1024
#define NT    16    // GEMM K-tiles (1024 / 64)
#define ST    48    // marginal buckets (6 concepts x 8)
#define LOG2E 1.44269504088896340736f

// async global->LDS, 16B per lane; LDS dst is wave-uniform base + lane*16
#define GLL(gsrc, ldst) \
  __builtin_amdgcn_global_load_lds((const __attribute__((address_space(1))) u32*)(gsrc), \
                                   (__attribute__((address_space(3))) u32*)(ldst), 16, 0, 0)
#define FENCE asm volatile("" ::: "memory")

// ---------------- prep: E/W f32->bf16 + swizzle-baked S2^T, one launch ----
// s2t[b][ig] = indicator(digit_c(vs[ig ^ ((b&7)<<3)]) == d), b = c*8+d
// (the XOR bakes the epilogue's 16B-chunk LDS swizzle; rule #21 both-sides).
__global__ void prep_kernel(const float* __restrict__ E, const float* __restrict__ W,
                            const int* __restrict__ vs,
                            bf16_t* __restrict__ Eb, bf16_t* __restrict__ Wb,
                            bf16_t* __restrict__ s2t) {
  const int nE = BROWS * KD / 4;       // float4 units
  const int nW = NV * KD / 4;
  const int nS = ST * NV / 8;          // bf16x8 units
  const int nT = nE + nW + nS;
  int idx = blockIdx.x * blockDim.x + threadIdx.x;
  int stride = gridDim.x * blockDim.x;
  for (int i = idx; i < nT; i += stride) {
    if (i < nE + nW) {
      const float4* s; bf16x4* d; int j;
      if (i < nE) { s = (const float4*)E; d = (bf16x4*)Eb; j = i; }
      else        { s = (const float4*)W; d = (bf16x4*)Wb; j = i - nE; }
      float4 v = s[j];
      bf16x4 o;
      o[0] = (bf16_t)v.x; o[1] = (bf16_t)v.y; o[2] = (bf16_t)v.z; o[3] = (bf16_t)v.w;
      d[j] = o;
    } else {
      int u  = i - nE - nW;            // bf16x8 unit of s2t
      int b  = u >> 10;                // bucket row (NV/8 = 1024 units/row)
      int i0 = (u & 1023) * 8;
      int base = i0 ^ ((b & 7) << 3);  // swizzle-baked source index
      int c = b >> 3, d = b & 7, sh = 15 - 3 * c;
      bf16x8 o;
#pragma unroll
      for (int e = 0; e < 8; ++e)
        o[e] = (bf16_t)((((vs[base + e] >> sh) & 7) == d) ? 1.0f : 0.0f);
      *(bf16x8*)(s2t + (size_t)b * NV + i0) = o;
    }
  }
}

// ---------------- fused GEMM + exp + marginal (R6/R10 structure, best measured) --
// D[i=state][j=batch] = sum_k W[i][k]*E[j][k]; 256x256 tile, BK=64, 8 waves
// (wm: 2 state-halves x wn: 4 batch-quarters), 128 KiB dbuf LDS.
// ONE barrier per K-tile; in-window pipeline: [12 kh0 ds_reads | 8 GLL next
// tile | 12 kh1 ds_reads] -> 32 MFMA kh0 -> 32 MFMA kh1 -> vmcnt(0) ->
// s_barrier. EXACT R6/R10 instruction order — 9 measured perturbations
// (R4/5/7/8/9/11/12/14 + 32x32 shape) are all slower; do not perturb.
// Swizzle (T2, 64B rows): phys = logical ^ ((row&6)<<3); staging source
// pre-permuted kslot = (l&3)^((l>>3)&3) (both-sides involution, rule #21).
__global__ __launch_bounds__(512, 2)
void gemm_fused_kernel(const bf16_t* __restrict__ W, const bf16_t* __restrict__ E,
                       const float* __restrict__ bias, const bf16_t* __restrict__ s2t,
                       float* __restrict__ part) {
  __shared__ __align__(16) char lds[2][65536];
  #define AKH0 0
  #define AKH1 16384
  #define BKH0 32768
  #define BKH1 49152

  const int t    = threadIdx.x;
  const int lane = t & 63;
  const int wv   = t >> 6;      // 0..7
  const int wm   = wv >> 2;     // 0..1  (state half)
  const int wn   = wv & 3;      // 0..3  (batch quarter)
  const int fr   = lane & 15;
  const int fq   = lane >> 4;

  // XCD swizzle: 512 blocks % 8 == 0 -> simple form bijective
  int bid = blockIdx.x;
  int wg  = (bid & 7) * 64 + (bid >> 3);
  const int stile = wg >> 4;    // 0..31 (state tile)
  const int btile = wg & 15;    // 0..15 (batch tile)
  const int st0 = stile * 256;
  const int bt0 = btile * 256;

  // ---- staging geometry: half-tile = 256 rows x 32 k = 16KB = 16 chunks ----
  const int srow = lane >> 2;
  const int skel = ((lane & 3) ^ ((lane >> 3) & 3)) * 8;
  const bf16_t* aptr = W + (size_t)(st0 + wv * 32 + srow) * KD + skel;
  const bf16_t* bptr = E + (size_t)(bt0 + wv * 32 + srow) * KD + skel;
  const int dchunk = (wv * 2) * 1024;

  // ---- ds_read geometry: row stride 64B; phys = logical ^ ((row&6)<<3) ----
  const int xsw    = (fr & 6) << 3;
  const int a_base = wm * 8192 + ((fr * 64 + fq * 16) ^ xsw);
  const int b_base = wn * 4096 + ((fr * 64 + fq * 16) ^ xsw);

  f32x4 acc[8][4] = {};

  // ---- prologue: stage kt0, drain, barrier ----
  GLL(aptr,                &lds[0][AKH0 + dchunk]);
  GLL(aptr + 16 * KD,      &lds[0][AKH0 + dchunk + 1024]);
  GLL(bptr,                &lds[0][BKH0 + dchunk]);
  GLL(bptr + 16 * KD,      &lds[0][BKH0 + dchunk + 1024]);
  GLL(aptr + 32,           &lds[0][AKH1 + dchunk]);
  GLL(aptr + 32 + 16 * KD, &lds[0][AKH1 + dchunk + 1024]);
  GLL(bptr + 32,           &lds[0][BKH1 + dchunk]);
  GLL(bptr + 32 + 16 * KD, &lds[0][BKH1 + dchunk + 1024]);
  asm volatile("s_waitcnt vmcnt(0)" ::: "memory");
  __builtin_amdgcn_s_barrier();
  FENCE;

  int cur = 0;
  for (int kt = 0; kt < NT; ++kt) {
    const char* bufp = lds[cur];
    char* nbuf = lds[cur ^ 1];
    const bool pf = (kt + 1 < NT);

    bf16x8 a0[8], b0[4], a1[8], b1[4];

    // kh0 fragment reads (12 x ds_read_b128)
#pragma unroll
    for (int n = 0; n < 4; ++n)
      b0[n] = *(const bf16x8*)(bufp + b_base + BKH0 + n * 1024);
#pragma unroll
    for (int m = 0; m < 8; ++m)
      a0[m] = *(const bf16x8*)(bufp + a_base + AKH0 + m * 1024);

    // stage next K-tile into the other buffer (8 x global_load_lds)
    if (pf) {
      const bf16_t* an = aptr + (kt + 1) * 64;
      const bf16_t* bn = bptr + (kt + 1) * 64;
      GLL(an,                &nbuf[AKH0 + dchunk]);
      GLL(an + 16 * KD,      &nbuf[AKH0 + dchunk + 1024]);
      GLL(bn,                &nbuf[BKH0 + dchunk]);
      GLL(bn + 16 * KD,      &nbuf[BKH0 + dchunk + 1024]);
      GLL(an + 32,           &nbuf[AKH1 + dchunk]);
      GLL(an + 32 + 16 * KD, &nbuf[AKH1 + dchunk + 1024]);
      GLL(bn + 32,           &nbuf[BKH1 + dchunk]);
      GLL(bn + 32 + 16 * KD, &nbuf[BKH1 + dchunk + 1024]);
    }

    // kh1 fragment reads (12 x ds_read_b128) — fly during kh0 MFMA
#pragma unroll
    for (int n = 0; n < 4; ++n)
      b1[n] = *(const bf16x8*)(bufp + b_base + BKH1 + n * 1024);
#pragma unroll
    for (int m = 0; m < 8; ++m)
      a1[m] = *(const bf16x8*)(bufp + a_base + AKH1 + m * 1024);

    __builtin_amdgcn_s_setprio(1);
#pragma unroll
    for (int m = 0; m < 8; ++m)
#pragma unroll
      for (int n = 0; n < 4; ++n)
        acc[m][n] = __builtin_amdgcn_mfma_f32_16x16x32_bf16(a0[m], b0[n], acc[m][n], 0, 0, 0);
#pragma unroll
    for (int m = 0; m < 8; ++m)
#pragma unroll
      for (int n = 0; n < 4; ++n)
        acc[m][n] = __builtin_amdgcn_mfma_f32_16x16x32_bf16(a1[m], b1[n], acc[m][n], 0, 0, 0);
    __builtin_amdgcn_s_setprio(0);

    asm volatile("s_waitcnt vmcnt(0)" ::: "memory");
    __builtin_amdgcn_sched_barrier(0);
    __builtin_amdgcn_s_barrier();
    FENCE;
    cur ^= 1;
  }

  // ================= fused epilogue (R6/R10 structure) =================
  // exp-tile [128 rows][512B] at 0, XOR-swizzled; s2t tile [48][512B] at 65536
  // (swizzle baked into s2t by prep_kernel).
  char* const ldsf = &lds[0][0];
  {
#pragma unroll
    for (int q = 0; q < 3; ++q) {
      const bf16_t* src = s2t + (size_t)(wv * 6 + q * 2 + (lane >> 5)) * NV
                          + st0 + (lane & 31) * 8;
      GLL(src, ldsf + 65536 + wv * 3072 + q * 1024);
    }
  }

  // part layout: [batch][stile][ST]  (contiguous 1536 floats per batch row)
  float* const ppart = part + (size_t)bt0 * (32 * ST) + (size_t)stile * ST;

#pragma unroll
  for (int pass = 0; pass < 2; ++pass) {
    if ((wn >> 1) == pass) {
#pragma unroll
      for (int m = 0; m < 8; ++m) {
        const float4 bb = *(const float4*)&bias[st0 + wm * 128 + m * 16 + fq * 4];
#pragma unroll
        for (int n = 0; n < 4; ++n) {
          bf16x4 ev;
          ev[0] = (bf16_t)exp2f((acc[m][n][0] + bb.x) * LOG2E);
          ev[1] = (bf16_t)exp2f((acc[m][n][1] + bb.y) * LOG2E);
          ev[2] = (bf16_t)exp2f((acc[m][n][2] + bb.z) * LOG2E);
          ev[3] = (bf16_t)exp2f((acc[m][n][3] + bb.w) * LOG2E);
          const int jh = (wn & 1) * 64 + n * 16 + fr;          // half-local batch row
          const int ib = (wm * 128 + m * 16 + fq * 4) * 2;     // state byte offset
          *(bf16x4*)(ldsf + jh * 512 + (ib ^ ((fr & 7) << 4))) = ev;
        }
      }
    }
    if (pass == 0) asm volatile("s_waitcnt vmcnt(0)" ::: "memory");  // S2T resident
    __syncthreads();

    // marginal MFMA (16x16x32): D[j_local][bucket] = exp-tile . S
    f32x4 acc2[3] = {{0.f,0.f,0.f,0.f},{0.f,0.f,0.f,0.f},{0.f,0.f,0.f,0.f}};
#pragma unroll
    for (int k2 = 0; k2 < 8; ++k2) {
      const int ko2 = (k2 * 64 + fq * 16) ^ ((fr & 7) << 4);
      const bf16x8 ea = *(const bf16x8*)(ldsf + (wv * 16 + fr) * 512 + ko2);
#pragma unroll
      for (int n2 = 0; n2 < 3; ++n2) {
        const bf16x8 sb = *(const bf16x8*)(ldsf + 65536 + (n2 * 16 + fr) * 512 + ko2);
        acc2[n2] = __builtin_amdgcn_mfma_f32_16x16x32_bf16(ea, sb, acc2[n2], 0, 0, 0);
      }
    }
    const int jg = pass * 128 + wv * 16 + fq * 4;
#pragma unroll
    for (int n2 = 0; n2 < 3; ++n2)
#pragma unroll
      for (int r = 0; r < 4; ++r)
        ppart[(size_t)(jg + r) * (32 * ST) + n2 * 16 + fr] = acc2[n2][r];
    __syncthreads();
  }
}

// ---------------- reduce partials over 32 state-tiles + normalize ----------------
// part[batch][stile][ST] contiguous 6 KB per batch row; wave w -> batch b0+w.
__global__ __launch_bounds__(256)
void reduce_kernel(const float* __restrict__ part, float* __restrict__ out) {
  const int w    = threadIdx.x >> 6;
  const int lane = threadIdx.x & 63;
  const int b    = blockIdx.x * 4 + w;

  const float* p = part + (size_t)b * (32 * ST);
  __shared__ float red[4][ST];
  if (lane < ST) {
    float acc = 0.f;
#pragma unroll
    for (int mt = 0; mt < 32; ++mt)
      acc += p[mt * ST + lane];
    red[w][lane] = acc;
  }
  __syncthreads();
  if (lane < ST) {
    const float* fin = red[w];
    float total = fin[0] + fin[1] + fin[2] + fin[3] + fin[4] + fin[5] + fin[6] + fin[7];
    out[(size_t)(lane >> 3) * BROWS * 8 + (size_t)b * 8 + (lane & 7)] = red[w][lane] / total;
  }
}

// ---------------- launch ----------------
extern "C" void kernel_launch(void* const* d_in, const int* in_sizes, int n_in,
                              void* d_out, int out_size, void* d_ws, size_t ws_size,
                              hipStream_t stream) {
  const float* E    = (const float*)d_in[0];
  const float* W    = (const float*)d_in[1];
  const float* bias = (const float*)d_in[2];
  const int*   vs   = (const int*)d_in[3];
  float* out = (float*)d_out;

  char* ws = (char*)d_ws;
  size_t off = 0;
  bf16_t* Eb   = (bf16_t*)(ws + off); off += (size_t)BROWS * KD * 2;           // 8 MB
  bf16_t* Wb   = (bf16_t*)(ws + off); off += (size_t)NV * KD * 2;              // 16 MB
  bf16_t* s2t  = (bf16_t*)(ws + off); off += (size_t)ST * NV * 2;              // 786 KB
  float*  part = (float*)(ws + off);  off += (size_t)BROWS * 32 * ST * 4;      // 25 MB

  prep_kernel<<<3072, 256, 0, stream>>>(E, W, vs, Eb, Wb, s2t);
  gemm_fused_kernel<<<512, 512, 0, stream>>>(Wb, Eb, bias, s2t, part);
  reduce_kernel<<<BROWS / 4, 256, 0, stream>>>(part, out);
}